// Round 1
// baseline (1074.184 us; speedup 1.0000x reference)
//
#include <hip/hip_runtime.h>
#include <math.h>

// Problem constants
constexpr int CB = 16, CT = 100, CMCL = 100, CDIN = 200, CDBERT = 768;
constexpr int CKC = 50, CKCD = 100, CHID = 128, CSB = 100;
constexpr int XCH = 1330;          // channels of x
constexpr int NBT = CB * CT;       // 1600
constexpr int NNODE = 10002, NPATH = 20002;

// Workspace layout (float offsets)
constexpr long O_T0a = 0;
constexpr long O_T0c = O_T0a + (long)NNODE * 500;
constexpr long O_TPp = O_T0c + (long)NNODE * 500;
constexpr long O_U0a = O_TPp + (long)NPATH * 500;
constexpr long O_U0c = O_U0a + (long)NNODE * 100;
constexpr long O_UPp = O_U0c + (long)NNODE * 100;
constexpr long O_R   = O_UPp + (long)NPATH * 100;
constexpr long O_RW  = O_R   + (long)NBT * 500;
constexpr long O_cw  = O_RW  + (long)NBT * 100;
constexpr long O_aw  = O_cw  + (long)NBT * 100;   // cw stored as [b][m][t]
constexpr long O_rnn = O_aw  + (long)NBT * 100;
constexpr long O_pre = O_rnn + (long)NBT * 950;
constexpr long O_lstm= O_pre + (long)NBT * 512;
constexpr long O_w   = O_lstm+ (long)NBT * 128;
constexpr long O_WfcT= O_w   + NBT;
constexpr long WS_FLOATS = O_WfcT + 378L * 100;

__device__ __forceinline__ float fsigmoid(float v){ return 1.f/(1.f+__expf(-v)); }
__device__ __forceinline__ float ftanh_(float v){
  float e = __expf(-2.f*fabsf(v));
  return copysignf((1.f-e)/(1.f+e), v);
}
__device__ __forceinline__ float wredsum(float v){
  #pragma unroll
  for (int off = 32; off; off >>= 1) v += __shfl_xor(v, off);
  return v;
}
__device__ __forceinline__ float wredmax(float v){
  #pragma unroll
  for (int off = 32; off; off >>= 1) v = fmaxf(v, __shfl_xor(v, off));
  return v;
}

// ------------------------- generic fp32 GEMM: C = A(MxK) * B(NxK)^T + bias -------------------------
template<int BM, int BN, int TM, int TN>
__global__ __launch_bounds__(256) void gemm_nt(
    const float* __restrict__ A, int lda,
    const float* __restrict__ B, int ldb,
    float* __restrict__ C, int ldc,
    int M, int N, int K,
    const float* __restrict__ bias1, const float* __restrict__ bias2)
{
  constexpr int BK = 16;
  __shared__ __align__(16) float As[BK][BM];
  __shared__ __align__(16) float Bs[BK][BN];
  constexpr int TX = BN / TN;
  constexpr int TY = BM / TM;
  static_assert(TX * TY == 256, "bad cfg");
  const int tid = threadIdx.x;
  const int tx = tid % TX, ty = tid / TX;
  const int bm = blockIdx.x * BM, bn = blockIdx.y * BN;
  float acc[TM][TN] = {};
  constexpr int ELA = BM * BK / 256;
  constexpr int ELB = BN * BK / 256;
  for (int k0 = 0; k0 < K; k0 += BK) {
    #pragma unroll
    for (int i = 0; i < ELA; ++i) {
      int e = tid * ELA + i;
      int m = e >> 4, k = e & 15;
      int gm = bm + m, gk = k0 + k;
      As[k][m] = (gm < M && gk < K) ? A[(long)gm * lda + gk] : 0.f;
    }
    #pragma unroll
    for (int i = 0; i < ELB; ++i) {
      int e = tid * ELB + i;
      int n = e >> 4, k = e & 15;
      int gn = bn + n, gk = k0 + k;
      Bs[k][n] = (gn < N && gk < K) ? B[(long)gn * ldb + gk] : 0.f;
    }
    __syncthreads();
    #pragma unroll
    for (int k = 0; k < BK; ++k) {
      float a[TM], bv[TN];
      #pragma unroll
      for (int i = 0; i < TM; ++i) a[i] = As[k][ty*TM + i];
      #pragma unroll
      for (int j = 0; j < TN; ++j) bv[j] = Bs[k][tx*TN + j];
      #pragma unroll
      for (int i = 0; i < TM; ++i)
        #pragma unroll
        for (int j = 0; j < TN; ++j)
          acc[i][j] = fmaf(a[i], bv[j], acc[i][j]);
    }
    __syncthreads();
  }
  #pragma unroll
  for (int i = 0; i < TM; ++i) {
    int gm = bm + ty*TM + i;
    if (gm >= M) continue;
    #pragma unroll
    for (int j = 0; j < TN; ++j) {
      int gn = bn + tx*TN + j;
      if (gn >= N) continue;
      float v = acc[i][j];
      if (bias1) v += bias1[gn];
      if (bias2) v += bias2[gn];
      C[(long)gm * ldc + gn] = v;
    }
  }
}

// ------------------------- cw: per (b,t), all m: tanh(sum of table rows) . Wattn -------------------------
__global__ __launch_bounds__(256) void cw_kernel(
    const float* __restrict__ x, const float* __restrict__ T0a, const float* __restrict__ T0c,
    const float* __restrict__ TPp, const float* __restrict__ R, const float* __restrict__ Wattn,
    const float* __restrict__ battn, float* __restrict__ cwT)
{
  int bt = blockIdx.x; int b = bt / CT, t = bt % CT;
  int tid = threadIdx.x, w = tid >> 6, lane = tid & 63;
  __shared__ float Rl[500], Wl[500];
  for (int i = tid; i < 500; i += 256) { Rl[i] = R[(long)bt*500 + i]; Wl[i] = Wattn[i]; }
  __syncthreads();
  float bat = battn[0];
  for (int m = w; m < CMCL; m += 4) {
    long xb = (long)bt * XCH + 200 + 3*m;
    int ai = (int)x[xb], pi = (int)x[xb+1], ci = (int)x[xb+2];
    const float* pa = T0a + (long)ai * 500;
    const float* pc = T0c + (long)ci * 500;
    const float* pp = TPp + (long)pi * 500;
    float acc = 0.f;
    for (int d = lane; d < 500; d += 64) {
      float v = pa[d] + pc[d] + pp[d] + Rl[d];
      acc = fmaf(ftanh_(v), Wl[d], acc);
    }
    acc = wredsum(acc);
    if (lane == 0) cwT[((long)b*CMCL + m)*CT + t] = acc + bat;
  }
}

// ------------------------- aw: softmax over t for each (b,m) -------------------------
__global__ void aw_kernel(const float* __restrict__ cwT, float* __restrict__ awT)
{
  int bm = blockIdx.x; int lane = threadIdx.x;   // 64 threads
  const float* row = cwT + (long)bm * CT;
  bool h1 = lane < (CT - 64);
  float v0 = row[lane];
  float v1 = h1 ? row[64 + lane] : -3.0e38f;
  float mx = wredmax(fmaxf(v0, v1));
  float e0 = __expf(v0 - mx);
  float e1 = h1 ? __expf(v1 - mx) : 0.f;
  float s = wredsum(e0 + e1);
  float inv = 1.f / s;
  awT[(long)bm*CT + lane] = e0 * inv;
  if (h1) awT[(long)bm*CT + 64 + lane] = e1 * inv;
}

// ------------------------- fused: na + trans(LDS) + kc-attention -> rnn_input[0:850] -------------------------
__global__ __launch_bounds__(256) void fuse_kernel(
    const float* __restrict__ x,
    const float* __restrict__ node_emb, const float* __restrict__ path_emb,
    const float* __restrict__ U0a, const float* __restrict__ U0c, const float* __restrict__ UPp,
    const float* __restrict__ RW, const float* __restrict__ awT, const float* __restrict__ kc_emb,
    float* __restrict__ rnn)
{
  int bt = blockIdx.x; int b = bt / CT, t = bt % CT;
  int tid = threadIdx.x, w = tid >> 6, lane = tid & 63;
  __shared__ float tr_s[100][101];
  __shared__ float RWl[100], aw_s[100], kcl[64];
  __shared__ float na_red[4][304];
  __shared__ float ia_red[4][100];
  __shared__ int act_k[50];
  __shared__ int nact_s; __shared__ float kcn_s, awsum_s;

  if (tid < 100) { RWl[tid] = RW[(long)bt*100 + tid]; aw_s[tid] = awT[((long)b*CMCL + tid)*CT + t]; }
  if (tid < CKC) kcl[tid] = x[(long)bt*XCH + 1280 + tid];
  __syncthreads();
  if (tid == 0) {
    float kcn = 0.f; int na = 0;
    for (int k = 0; k < CKC; ++k) { float v = kcl[k]; kcn += v; if (v != 0.f) act_k[na++] = k; }
    nact_s = na; kcn_s = (kcn == 0.f) ? 1.f : kcn;
    float s = 0.f;
    for (int m = 0; m < CMCL; ++m) s += aw_s[m];
    awsum_s = s;
  }
  __syncthreads();

  const int d0 = lane, d1 = 64 + lane;
  const bool v1 = lane < 36;
  float na_a0=0, na_a1=0, na_c0=0, na_c1=0, na_p0=0, na_p1=0;
  for (int m = w; m < CMCL; m += 4) {
    long xb = (long)bt * XCH + 200 + 3*m;
    int ai = (int)x[xb], pi = (int)x[xb+1], ci = (int)x[xb+2];
    float awm = aw_s[m];
    const float* ea = node_emb + (long)ai*100;
    const float* ec = node_emb + (long)ci*100;
    const float* ep = path_emb + (long)pi*100;
    const float* ua = U0a + (long)ai*100;
    const float* uc = U0c + (long)ci*100;
    const float* up = UPp + (long)pi*100;
    na_a0 = fmaf(awm, ea[d0], na_a0);
    na_c0 = fmaf(awm, ec[d0], na_c0);
    na_p0 = fmaf(awm, ep[d0], na_p0);
    tr_s[m][d0] = ua[d0] + uc[d0] + up[d0] + RWl[d0];
    if (v1) {
      na_a1 = fmaf(awm, ea[d1], na_a1);
      na_c1 = fmaf(awm, ec[d1], na_c1);
      na_p1 = fmaf(awm, ep[d1], na_p1);
      tr_s[m][d1] = ua[d1] + uc[d1] + up[d1] + RWl[d1];
    }
  }
  na_red[w][d0] = na_a0; na_red[w][100+d0] = na_c0; na_red[w][200+d0] = na_p0;
  if (v1) { na_red[w][d1] = na_a1; na_red[w][100+d1] = na_c1; na_red[w][200+d1] = na_p1; }
  __syncthreads();

  for (int i2 = tid; i2 < 500; i2 += 256) {
    float v;
    if (i2 < 300) v = na_red[0][i2] + na_red[1][i2] + na_red[2][i2] + na_red[3][i2];
    else v = awsum_s * x[(long)bt*XCH + (i2 - 300)];
    rnn[(long)bt*950 + 350 + i2] = v;
  }
  if (tid < CKC) rnn[(long)bt*950 + tid] = kcl[tid];
  for (int i2 = tid; i2 < CDIN; i2 += 256) rnn[(long)bt*950 + 50 + i2] = x[(long)bt*XCH + i2];

  // kc attention
  float ia0 = 0.f, ia1 = 0.f;
  int nact = nact_s;
  for (int ki = w; ki < nact; ki += 4) {
    int k = act_k[ki];
    float kck = kcl[k];
    const float* ke = kc_emb + (long)k*100;
    float s0 = 0.f, s1 = 0.f;
    for (int d = 0; d < 100; ++d) {
      float kv = ke[d];
      s0 = fmaf(kv, tr_s[lane][d], s0);
      if (v1) s1 = fmaf(kv, tr_s[d1][d], s1);
    }
    s0 *= kck; s1 *= kck;
    float mx = wredmax(fmaxf(s0, v1 ? s1 : -3.0e38f));
    float p0 = __expf(s0 - mx);
    float p1 = v1 ? __expf(s1 - mx) : 0.f;
    float sm = wredsum(p0 + p1);
    float inv = kck / sm;
    p0 *= inv; p1 *= inv;
    for (int m = 0; m < 100; ++m) {
      float pm = (m < 64) ? __shfl(p0, m) : __shfl(p1, m - 64);
      ia0 = fmaf(pm, tr_s[m][d0], ia0);
      if (v1) ia1 = fmaf(pm, tr_s[m][d1], ia1);
    }
  }
  ia_red[w][d0] = ia0;
  if (v1) ia_red[w][d1] = ia1;
  __syncthreads();
  if (tid < 100) {
    float v = (ia_red[0][tid] + ia_red[1][tid] + ia_red[2][tid] + ia_red[3][tid]) / kcn_s;
    rnn[(long)bt*950 + 250 + tid] = v;
  }
}

// ------------------------- LSTM: one block per batch, Whh in registers -------------------------
__global__ __launch_bounds__(512) void lstm_kernel(
    const float* __restrict__ pre, const float* __restrict__ Whh,
    float* __restrict__ lstm_out)
{
  int b = blockIdx.x; int g = threadIdx.x;  // 0..511
  __shared__ __align__(16) float h_s[128];
  __shared__ float g_s[512];
  float4 wr[32];
  #pragma unroll
  for (int j = 0; j < 32; ++j) wr[j] = reinterpret_cast<const float4*>(Whh + (long)g*128)[j];
  float c_reg = 0.f;
  if (g < 128) h_s[g] = 0.f;
  __syncthreads();
  for (int t = 0; t < CT; ++t) {
    float s0=0,s1=0,s2=0,s3=0;
    #pragma unroll
    for (int j = 0; j < 32; ++j) {
      float4 hh = reinterpret_cast<const float4*>(h_s)[j];
      s0 = fmaf(wr[j].x, hh.x, s0);
      s1 = fmaf(wr[j].y, hh.y, s1);
      s2 = fmaf(wr[j].z, hh.z, s2);
      s3 = fmaf(wr[j].w, hh.w, s3);
    }
    float gv = pre[((long)b*CT + t)*512 + g] + ((s0+s1)+(s2+s3));
    g_s[g] = gv;
    __syncthreads();
    if (g < 128) {
      float ig = fsigmoid(g_s[g]);
      float fg = fsigmoid(g_s[128+g]);
      float gg = ftanh_(g_s[256+g]);
      float og = fsigmoid(g_s[384+g]);
      c_reg = fg*c_reg + ig*gg;
      float h = og * ftanh_(c_reg);
      h_s[g] = h;
      lstm_out[((long)b*CT + t)*128 + g] = h;
    }
    __syncthreads();
  }
}

// ------------------------- w: dot over [bert_vec, kc, ia] segments of rnn_input -------------------------
__global__ void w_kernel(const float* __restrict__ rnn, const float* __restrict__ Wt,
                         const float* __restrict__ bt0, float* __restrict__ wbuf)
{
  int bt = blockIdx.x; int lane = threadIdx.x; // 64 threads
  float acc = 0.f;
  for (int i = lane; i < 250; i += 64) {
    float f;
    if (i < 100)      f = rnn[(long)bt*950 + 850 + i];
    else if (i < 150) f = rnn[(long)bt*950 + (i - 100)];
    else              f = rnn[(long)bt*950 + 250 + (i - 150)];
    acc = fmaf(Wt[i], f, acc);
  }
  acc = wredsum(acc);
  if (lane == 0) wbuf[bt] = acc + bt0[0];
}

__global__ void transpose_wfc(const float* __restrict__ Wfc, float* __restrict__ WfcT)
{
  int i = blockIdx.x*256 + threadIdx.x;
  if (i < 100*378) { int o = i / 378, q = i % 378; WfcT[q*100 + o] = Wfc[i]; }
}

// ------------------------- final: causal softmax attention + attended + FC + sigmoid -------------------------
__global__ __launch_bounds__(256) void final_kernel(
    const float* __restrict__ x, const float* __restrict__ wbuf,
    const float* __restrict__ lstm_out, const float* __restrict__ WfcT,
    const float* __restrict__ bfc, float* __restrict__ out)
{
  int bt = blockIdx.x; int b = bt / CT, i = bt % CT;
  int tid = threadIdx.x;
  __shared__ float p_s[CT];
  __shared__ float feat_s[384];
  if (tid < 64) {
    bool h1 = (64 + tid) < CT;
    float v0 = (tid <= i) ? wbuf[(long)b*CT + tid] : -3.0e38f;
    float v1 = (h1 && (64 + tid) <= i) ? wbuf[(long)b*CT + 64 + tid] : -3.0e38f;
    float mx = wredmax(fmaxf(v0, v1));
    float e0 = (tid <= i) ? __expf(v0 - mx) : 0.f;
    float e1 = (h1 && (64 + tid) <= i) ? __expf(v1 - mx) : 0.f;
    float s = wredsum(e0 + e1);
    float inv = 1.f / s;
    p_s[tid] = e0 * inv;
    if (h1) p_s[64 + tid] = e1 * inv;
  }
  __syncthreads();
  if (tid < CHID) {
    float cur = 0.f;
    for (int j = 0; j <= i; ++j) cur = fmaf(p_s[j], lstm_out[((long)b*CT + j)*CHID + tid], cur);
    float l = lstm_out[((long)b*CT + i)*CHID + tid];
    float att;
    if (i == 0) att = l;
    else { att = 0.5f * l; if (i <= CT - 2) att = fmaf(0.5f, cur, att); }
    feat_s[250 + tid] = att;
  }
  for (int q = tid; q < 250; q += 256)
    feat_s[q] = (q < 200) ? x[(long)bt*XCH + q] : x[(long)bt*XCH + 1280 + (q - 200)];
  __syncthreads();
  if (tid < 100) {
    float acc = bfc[tid];
    for (int q = 0; q < 378; ++q) acc = fmaf(WfcT[q*100 + tid], feat_s[q], acc);
    out[(long)bt*100 + tid] = fsigmoid(acc);
  }
}

extern "C" void kernel_launch(void* const* d_in, const int* in_sizes, int n_in,
                              void* d_out, int out_size, void* d_ws, size_t ws_size,
                              hipStream_t stream) {
  (void)in_sizes; (void)n_in; (void)out_size; (void)ws_size;
  const float* x        = (const float*)d_in[0];
  const float* node_emb = (const float*)d_in[1];
  const float* path_emb = (const float*)d_in[2];
  const float* Wb       = (const float*)d_in[3];
  const float* bb       = (const float*)d_in[4];
  const float* Wna      = (const float*)d_in[5];
  const float* bna      = (const float*)d_in[6];
  const float* Wia      = (const float*)d_in[7];
  const float* bia      = (const float*)d_in[8];
  const float* Wattn    = (const float*)d_in[9];
  const float* battn    = (const float*)d_in[10];
  const float* kc_emb   = (const float*)d_in[11];
  const float* Wt       = (const float*)d_in[12];
  const float* bt0      = (const float*)d_in[13];
  const float* Wih      = (const float*)d_in[14];
  const float* Whh      = (const float*)d_in[15];
  const float* bih      = (const float*)d_in[16];
  const float* bhh      = (const float*)d_in[17];
  const float* Wfc      = (const float*)d_in[18];
  const float* bfc      = (const float*)d_in[19];
  float* ws = (float*)d_ws;
  float* out = (float*)d_out;

  float* T0a = ws + O_T0a; float* T0c = ws + O_T0c; float* TPp = ws + O_TPp;
  float* U0a = ws + O_U0a; float* U0c = ws + O_U0c; float* UPp = ws + O_UPp;
  float* R   = ws + O_R;   float* RW  = ws + O_RW;
  float* cwT = ws + O_cw;  float* awT = ws + O_aw;
  float* rnn = ws + O_rnn; float* pre = ws + O_pre;
  float* lstm= ws + O_lstm;float* wbuf= ws + O_w;
  float* WfcT= ws + O_WfcT;

  auto grid = [](int M, int N, int BM, int BN){ return dim3((M+BM-1)/BM, (N+BN-1)/BN); };

  // Table GEMMs (Wna/Wia pushed through the gathers)
  gemm_nt<128,128,8,8><<<grid(NNODE,500,128,128),256,0,stream>>>(node_emb,100, Wna,500,      T0a,500, NNODE,500,100, nullptr,nullptr);
  gemm_nt<128,128,8,8><<<grid(NNODE,500,128,128),256,0,stream>>>(node_emb,100, Wna+100,500,  T0c,500, NNODE,500,100, nullptr,nullptr);
  gemm_nt<128,128,8,8><<<grid(NPATH,500,128,128),256,0,stream>>>(path_emb,100, Wna+200,500,  TPp,500, NPATH,500,100, nullptr,nullptr);
  gemm_nt<128,128,8,8><<<grid(NNODE,100,128,128),256,0,stream>>>(node_emb,100, Wia,500,      U0a,100, NNODE,100,100, nullptr,nullptr);
  gemm_nt<128,128,8,8><<<grid(NNODE,100,128,128),256,0,stream>>>(node_emb,100, Wia+100,500,  U0c,100, NNODE,100,100, nullptr,nullptr);
  gemm_nt<128,128,8,8><<<grid(NPATH,100,128,128),256,0,stream>>>(path_emb,100, Wia+200,500,  UPp,100, NPATH,100,100, nullptr,nullptr);
  // Per-(b,t) contributions (fold biases here)
  gemm_nt<64,64,4,4><<<grid(NBT,500,64,64),256,0,stream>>>(x,XCH, Wna+300,500, R,500,  NBT,500,CDIN, bna,nullptr);
  gemm_nt<64,64,4,4><<<grid(NBT,100,64,64),256,0,stream>>>(x,XCH, Wia+300,500, RW,100, NBT,100,CDIN, bia,nullptr);
  // bert_vec directly into rnn_input[850:950]
  gemm_nt<64,64,4,4><<<grid(NBT,100,64,64),256,0,stream>>>(x+500,XCH, Wb,CDBERT, rnn+850,950, NBT,100,CDBERT, bb,nullptr);

  cw_kernel<<<NBT,256,0,stream>>>(x, T0a, T0c, TPp, R, Wattn, battn, cwT);
  aw_kernel<<<CB*CMCL,64,0,stream>>>(cwT, awT);
  fuse_kernel<<<NBT,256,0,stream>>>(x, node_emb, path_emb, U0a, U0c, UPp, RW, awT, kc_emb, rnn);

  // LSTM input pre-activations
  gemm_nt<64,64,4,4><<<grid(NBT,512,64,64),256,0,stream>>>(rnn,950, Wih,950, pre,512, NBT,512,950, bih,bhh);
  lstm_kernel<<<CB,512,0,stream>>>(pre, Whh, lstm);

  w_kernel<<<NBT,64,0,stream>>>(rnn, Wt, bt0, wbuf);
  transpose_wfc<<<(100*378+255)/256,256,0,stream>>>(Wfc, WfcT);
  final_kernel<<<NBT,256,0,stream>>>(x, wbuf, lstm, WfcT, bfc, out);
}

// Round 2
// 980.605 us; speedup vs baseline: 1.0954x; 1.0954x over previous
//
#include <hip/hip_runtime.h>
#include <math.h>

typedef unsigned short ushort_t;
typedef __attribute__((ext_vector_type(8))) short bf16x8;
typedef __attribute__((ext_vector_type(4))) float f32x4;

// Problem constants
constexpr int CB = 16, CT = 100, CMCL = 100, CDIN = 200;
constexpr int CKC = 50, CHID = 128;
constexpr int XCH = 1330;
constexpr int NBT = CB * CT;       // 1600
constexpr int NNODE = 10002, NPATH = 20002;

__device__ __forceinline__ float fsigmoid(float v){ return 1.f/(1.f+__expf(-v)); }
__device__ __forceinline__ float ftanh_(float v){
  float e = __expf(-2.f*fabsf(v));
  return copysignf((1.f-e)/(1.f+e), v);
}
__device__ __forceinline__ float wredsum(float v){
  #pragma unroll
  for (int off = 32; off; off >>= 1) v += __shfl_xor(v, off);
  return v;
}
__device__ __forceinline__ float wredmax(float v){
  #pragma unroll
  for (int off = 32; off; off >>= 1) v = fmaxf(v, __shfl_xor(v, off));
  return v;
}
__device__ __forceinline__ ushort_t f2b(float f){
  union { float f; unsigned u; } c{f};
  return (ushort_t)((c.u + 0x7FFFu + ((c.u >> 16) & 1u)) >> 16);
}
__device__ __forceinline__ float b2f(unsigned hbits){
  union { unsigned u; float f; } c{hbits << 16};
  return c.f;
}
// load 8 bf16 (16B) and convert to 8 fp32
__device__ __forceinline__ void b8f(const ushort_t* p, float* o){
  uint4 v = *reinterpret_cast<const uint4*>(p);
  o[0]=b2f(v.x & 0xFFFFu); o[1]=b2f(v.x >> 16);
  o[2]=b2f(v.y & 0xFFFFu); o[3]=b2f(v.y >> 16);
  o[4]=b2f(v.z & 0xFFFFu); o[5]=b2f(v.z >> 16);
  o[6]=b2f(v.w & 0xFFFFu); o[7]=b2f(v.w >> 16);
}

// ---------------- MFMA bf16 GEMM: C = A(MxK,f32) * B(NxK,f32)^T (+bias), out f32 or bf16 ----------------
// BM=128, BN=64, BK=32, 4 waves (2m x 2n), wave tile 64x32 via 16x16x32 frags.
template<bool OUT_BF16>
__global__ __launch_bounds__(256) void gemm_mfma(
    const float* __restrict__ A, int lda,
    const float* __restrict__ B, int ldb,
    void* __restrict__ Cv, int ldc,
    int M, int N, int Npad, int K,
    const float* __restrict__ bias1, const float* __restrict__ bias2)
{
  __shared__ ushort_t As[128][40];   // stride 40 (80B) -> 2-way max on b128 reads (free)
  __shared__ ushort_t Bs[64][40];
  const int tid = threadIdx.x;
  const int lane = tid & 63, wid = tid >> 6;
  const int wm = wid & 1, wn = wid >> 1;
  const int bm = blockIdx.x * 128, bn = blockIdx.y * 64;
  const int lr = lane & 15, lk = (lane >> 4) * 8;

  f32x4 acc[4][2];
  #pragma unroll
  for (int i = 0; i < 4; ++i)
    #pragma unroll
    for (int j = 0; j < 2; ++j) acc[i][j] = f32x4{0.f,0.f,0.f,0.f};

  const int arow = tid >> 1, akh = (tid & 1) * 16;
  const int brow = tid >> 2, bkh = (tid & 3) * 8;
  const int nk = (K + 31) / 32;
  for (int ks = 0; ks < nk; ++ks) {
    const int k0 = ks * 32;
    { // stage A: 128 rows x 32 k
      int gm = bm + arow;
      const float* ap = A + (long)gm * lda + k0 + akh;
      #pragma unroll
      for (int j = 0; j < 8; ++j) {
        int kk = k0 + akh + 2*j;
        float2 v = make_float2(0.f, 0.f);
        if (gm < M && kk + 2 <= K) v = *reinterpret_cast<const float2*>(ap + 2*j);
        As[arow][akh + 2*j]     = f2b(v.x);
        As[arow][akh + 2*j + 1] = f2b(v.y);
      }
    }
    { // stage B: 64 rows x 32 k
      int gn = bn + brow;
      const float* bp = B + (long)gn * ldb + k0 + bkh;
      #pragma unroll
      for (int j = 0; j < 4; ++j) {
        int kk = k0 + bkh + 2*j;
        float2 v = make_float2(0.f, 0.f);
        if (gn < N && kk + 2 <= K) v = *reinterpret_cast<const float2*>(bp + 2*j);
        Bs[brow][bkh + 2*j]     = f2b(v.x);
        Bs[brow][bkh + 2*j + 1] = f2b(v.y);
      }
    }
    __syncthreads();
    bf16x8 af[4], bf[2];
    #pragma unroll
    for (int i = 0; i < 4; ++i)
      af[i] = *reinterpret_cast<const bf16x8*>(&As[wm*64 + i*16 + lr][lk]);
    #pragma unroll
    for (int j = 0; j < 2; ++j)
      bf[j] = *reinterpret_cast<const bf16x8*>(&Bs[wn*32 + j*16 + lr][lk]);
    #pragma unroll
    for (int i = 0; i < 4; ++i)
      #pragma unroll
      for (int j = 0; j < 2; ++j)
        acc[i][j] = __builtin_amdgcn_mfma_f32_16x16x32_bf16(af[i], bf[j], acc[i][j], 0, 0, 0);
    __syncthreads();
  }
  // epilogue: D row=(lane>>4)*4+r, col=lane&15
  #pragma unroll
  for (int i = 0; i < 4; ++i) {
    #pragma unroll
    for (int j = 0; j < 2; ++j) {
      #pragma unroll
      for (int r = 0; r < 4; ++r) {
        int gr = bm + wm*64 + i*16 + (lane >> 4)*4 + r;
        int gc = bn + wn*32 + j*16 + lr;
        if (gr < M && gc < Npad) {
          float v = acc[i][j][r];
          if (gc < N) {
            if (bias1) v += bias1[gc];
            if (bias2) v += bias2[gc];
          } else v = 0.f;
          if (OUT_BF16) ((ushort_t*)Cv)[(long)gr * ldc + gc] = f2b(v);
          else          ((float*)Cv)[(long)gr * ldc + gc]  = v;
        }
      }
    }
  }
}

// ---------------- prep: pack embeddings into combined [emb(100)|pad12|U(100)|pad12] bf16 rows ----------------
__global__ void pack_emb(const float* __restrict__ emb, ushort_t* __restrict__ V, int rows)
{
  int i = blockIdx.x * 256 + threadIdx.x;
  int r = i / 112, c = i % 112;
  if (r < rows) V[(long)r*224 + c] = (c < 100) ? f2b(emb[(long)r*100 + c]) : (ushort_t)0;
}
__global__ void pack_wattn(const float* __restrict__ Wattn, ushort_t* __restrict__ wab)
{
  int i = blockIdx.x * 256 + threadIdx.x;
  if (i < 512) wab[i] = (i < 500) ? f2b(Wattn[i]) : (ushort_t)0;
}

// ---------------- cw: per (b,t), all m: Wattn . tanh(T0A[a]+T0C[c]+TPP[p]+R) ----------------
__global__ __launch_bounds__(256) void cw2_kernel(
    const float* __restrict__ x, const ushort_t* __restrict__ T0A,
    const ushort_t* __restrict__ T0C, const ushort_t* __restrict__ TPP,
    const ushort_t* __restrict__ RB, const ushort_t* __restrict__ WAB,
    const float* __restrict__ battn, float* __restrict__ cwT)
{
  int bt = blockIdx.x, b = bt / CT, t = bt % CT;
  int tid = threadIdx.x, w = tid >> 6, lane = tid & 63;
  __shared__ int idx_s[300];
  for (int i = tid; i < 300; i += 256) idx_s[i] = (int)x[(long)bt*XCH + 200 + i];
  float rseg[8], wseg[8];
  b8f(RB + (long)bt*512 + lane*8, rseg);
  b8f(WAB + lane*8, wseg);
  __syncthreads();
  float bat = battn[0];
  for (int m = w; m < CMCL; m += 4) {
    int ai = idx_s[3*m], pi = idx_s[3*m+1], ci = idx_s[3*m+2];
    float fa[8], fc[8], fp[8];
    b8f(T0A + (long)ai*512 + lane*8, fa);
    b8f(T0C + (long)ci*512 + lane*8, fc);
    b8f(TPP + (long)pi*512 + lane*8, fp);
    float acc = 0.f;
    #pragma unroll
    for (int j = 0; j < 8; ++j)
      acc = fmaf(ftanh_(fa[j]+fc[j]+fp[j]+rseg[j]), wseg[j], acc);
    acc = wredsum(acc);
    if (lane == 0) cwT[((long)b*CMCL + m)*CT + t] = acc + bat;
  }
}

// ---------------- aw: softmax over t for each (b,m) ----------------
__global__ void aw_kernel(const float* __restrict__ cwT, float* __restrict__ awT)
{
  int bm = blockIdx.x; int lane = threadIdx.x;   // 64 threads
  const float* row = cwT + (long)bm * CT;
  bool h1 = lane < (CT - 64);
  float v0 = row[lane];
  float v1 = h1 ? row[64 + lane] : -3.0e38f;
  float mx = wredmax(fmaxf(v0, v1));
  float e0 = __expf(v0 - mx);
  float e1 = h1 ? __expf(v1 - mx) : 0.f;
  float s = wredsum(e0 + e1);
  float inv = 1.f / s;
  awT[(long)bm*CT + lane] = e0 * inv;
  if (h1) awT[(long)bm*CT + 64 + lane] = e1 * inv;
}

// tr_s accessor: row stride 112 ushorts, 8-elem blocks rotated by (m % 14)
__device__ __forceinline__ int tr_blk(int db, int mr){ int b = db + mr; return (b >= 14) ? b - 14 : b; }

// ---------------- fused: na + trans(LDS bf16) + kc-attention -> rnn[0:850] ----------------
__global__ __launch_bounds__(256) void fuse2_kernel(
    const float* __restrict__ x,
    const ushort_t* __restrict__ VA, const ushort_t* __restrict__ VC, const ushort_t* __restrict__ VP,
    const ushort_t* __restrict__ RWB, const float* __restrict__ awT,
    const float* __restrict__ kc_emb, float* __restrict__ rnn)
{
  int bt = blockIdx.x, b = bt / CT, t = bt % CT;
  int tid = threadIdx.x, w = tid >> 6, lane = tid & 63;
  int sub = lane >> 5, li = lane & 31;

  __shared__ ushort_t tr_s[100*112];
  __shared__ float nacc[4][344];
  __shared__ float ia_red[4][112];
  __shared__ float aw_s[100];
  __shared__ int   idx_s[300];
  __shared__ float kcl[CKC];
  __shared__ int   act_k[CKC];
  __shared__ int   nact_s;
  __shared__ float kcn_s, awsum_s;

  for (int i = tid; i < 300; i += 256) idx_s[i] = (int)x[(long)bt*XCH + 200 + i];
  if (tid < 100) aw_s[tid] = awT[((long)b*CMCL + tid)*CT + t];
  if (tid < CKC) kcl[tid] = x[(long)bt*XCH + 1280 + tid];
  __syncthreads();
  if (tid == 0) {
    float kcn = 0.f; int na = 0;
    for (int k = 0; k < CKC; ++k) { float v = kcl[k]; kcn += v; if (v != 0.f) act_k[na++] = k; }
    nact_s = na; kcn_s = (kcn == 0.f) ? 1.f : kcn;
    float s = 0.f;
    for (int m = 0; m < CMCL; ++m) s += aw_s[m];
    awsum_s = s;
  }
  float rwseg[8];
  const int uoff = li*8 - 112;     // valid for li >= 14
  if (li >= 14 && li < 28) b8f(RWB + (long)bt*112 + uoff, rwseg);
  __syncthreads();

  // ---- gather phase: 8 m per iteration (4 waves x 2 sub-halves) ----
  float na_a[8] = {}, na_c[8] = {}, na_p[8] = {};
  for (int it = 0; it < 13; ++it) {
    int m = it*8 + w*2 + sub;
    if (m < CMCL && li < 28) {
      int ai = idx_s[3*m], pi = idx_s[3*m+1], ci = idx_s[3*m+2];
      float fa[8], fc[8], fp[8];
      b8f(VA + (long)ai*224 + li*8, fa);
      b8f(VC + (long)ci*224 + li*8, fc);
      b8f(VP + (long)pi*224 + li*8, fp);
      if (li < 14) {
        float awm = aw_s[m];
        #pragma unroll
        for (int j = 0; j < 8; ++j) {
          na_a[j] = fmaf(awm, fa[j], na_a[j]);
          na_c[j] = fmaf(awm, fc[j], na_c[j]);
          na_p[j] = fmaf(awm, fp[j], na_p[j]);
        }
      } else {
        ushort_t tv[8];
        #pragma unroll
        for (int j = 0; j < 8; ++j) tv[j] = f2b(fa[j]+fc[j]+fp[j]+rwseg[j]);
        int mr = m % 14;
        int blk = tr_blk(li - 14, mr);
        uint4 pk;
        pk.x = (unsigned)tv[0] | ((unsigned)tv[1] << 16);
        pk.y = (unsigned)tv[2] | ((unsigned)tv[3] << 16);
        pk.z = (unsigned)tv[4] | ((unsigned)tv[5] << 16);
        pk.w = (unsigned)tv[6] | ((unsigned)tv[7] << 16);
        *reinterpret_cast<uint4*>(&tr_s[m*112 + blk*8]) = pk;
      }
    }
    // no barrier needed inside: each (w,sub,li) owns disjoint tr_s cells
  }
  // combine sub-halves of na
  #pragma unroll
  for (int j = 0; j < 8; ++j) {
    na_a[j] += __shfl_xor(na_a[j], 32);
    na_c[j] += __shfl_xor(na_c[j], 32);
    na_p[j] += __shfl_xor(na_p[j], 32);
  }
  if (lane < 14) {
    #pragma unroll
    for (int j = 0; j < 8; ++j) {
      nacc[w][      lane*8 + j] = na_a[j];
      nacc[w][112 + lane*8 + j] = na_c[j];
      nacc[w][224 + lane*8 + j] = na_p[j];
    }
  }
  __syncthreads();

  // ---- na epilogue + passthroughs ----
  for (int q = tid; q < 336; q += 256) {
    float v = nacc[0][q] + nacc[1][q] + nacc[2][q] + nacc[3][q];
    int seg = q / 112, col = q % 112;
    if (col < 100) rnn[(long)bt*950 + 350 + seg*100 + col] = v;
  }
  for (int q = tid; q < CDIN; q += 256) {
    float xv = x[(long)bt*XCH + q];
    rnn[(long)bt*950 + 50 + q] = xv;
    rnn[(long)bt*950 + 650 + q] = awsum_s * xv;
  }
  if (tid < CKC) rnn[(long)bt*950 + tid] = kcl[tid];

  // ---- kc attention (reads tr_s bf16) ----
  float ia0 = 0.f, ia1 = 0.f;
  const bool vl1 = lane < 36;
  const int nact = nact_s;
  const int mr0 = lane % 14;
  const int mr1 = (64 + lane) % 14;
  for (int ki = w; ki < nact; ki += 4) {
    int k = act_k[ki];
    float kck = kcl[k];
    const float* ke = kc_emb + (long)k*100;
    float s0 = 0.f, s1 = 0.f;
    const int base0 = lane*112, base1 = (64+lane)*112;
    for (int db = 0; db < 13; ++db) {
      int b0 = tr_blk(db, mr0), b1 = tr_blk(db, mr1);
      const ushort_t* p0 = &tr_s[base0 + b0*8];
      const ushort_t* p1 = &tr_s[base1 + b1*8];
      const int dmax = (db == 12) ? 4 : 8;
      #pragma unroll 8
      for (int j = 0; j < dmax; ++j) {
        float kv = ke[db*8 + j];
        s0 = fmaf(kv, b2f(p0[j]), s0);
        if (vl1) s1 = fmaf(kv, b2f(p1[j]), s1);
      }
    }
    s0 *= kck; s1 *= kck;
    float mx = wredmax(fmaxf(s0, vl1 ? s1 : -3.0e38f));
    float p0e = __expf(s0 - mx);
    float p1e = vl1 ? __expf(s1 - mx) : 0.f;
    float sm = wredsum(p0e + p1e);
    float inv = kck / sm;
    p0e *= inv; p1e *= inv;
    // PV: lane owns d0=lane, d1=64+lane
    const int db0 = lane >> 3, j0 = lane & 7;
    const int db1 = (64 + lane) >> 3, j1 = lane & 7;
    int mr = 0;
    for (int m = 0; m < CMCL; ++m) {
      float pm = (m < 64) ? __shfl(p0e, m) : __shfl(p1e, m - 64);
      ia0 = fmaf(pm, b2f(tr_s[m*112 + tr_blk(db0, mr)*8 + j0]), ia0);
      if (vl1) ia1 = fmaf(pm, b2f(tr_s[m*112 + tr_blk(db1, mr)*8 + j1]), ia1);
      if (++mr == 14) mr = 0;
    }
  }
  ia_red[w][lane] = ia0;
  if (vl1) ia_red[w][64 + lane] = ia1;
  __syncthreads();
  if (tid < 100) {
    float v = (ia_red[0][tid] + ia_red[1][tid] + ia_red[2][tid] + ia_red[3][tid]) / kcn_s;
    rnn[(long)bt*950 + 250 + tid] = v;
  }
}

// ---------------- LSTM: one block per batch, Whh rows in registers ----------------
__global__ __launch_bounds__(512) void lstm_kernel(
    const float* __restrict__ pre, const float* __restrict__ Whh,
    float* __restrict__ lstm_out)
{
  int b = blockIdx.x; int g = threadIdx.x;  // 0..511
  __shared__ __align__(16) float h_s[128];
  __shared__ float g_s[512];
  float4 wr[32];
  #pragma unroll
  for (int j = 0; j < 32; ++j) wr[j] = reinterpret_cast<const float4*>(Whh + (long)g*128)[j];
  float c_reg = 0.f;
  if (g < 128) h_s[g] = 0.f;
  float pf = pre[(long)b*CT*512 + g];
  __syncthreads();
  for (int t = 0; t < CT; ++t) {
    float gv_in = pf;
    if (t + 1 < CT) pf = pre[((long)b*CT + t + 1)*512 + g];  // prefetch next step
    float s0=0,s1=0,s2=0,s3=0;
    #pragma unroll
    for (int j = 0; j < 32; ++j) {
      float4 hh = reinterpret_cast<const float4*>(h_s)[j];
      s0 = fmaf(wr[j].x, hh.x, s0);
      s1 = fmaf(wr[j].y, hh.y, s1);
      s2 = fmaf(wr[j].z, hh.z, s2);
      s3 = fmaf(wr[j].w, hh.w, s3);
    }
    float gv = gv_in + ((s0+s1)+(s2+s3));
    __syncthreads();
    g_s[g] = gv;
    __syncthreads();
    if (g < 128) {
      float ig = fsigmoid(g_s[g]);
      float fg = fsigmoid(g_s[128+g]);
      float gg = ftanh_(g_s[256+g]);
      float og = fsigmoid(g_s[384+g]);
      c_reg = fg*c_reg + ig*gg;
      float h = og * ftanh_(c_reg);
      h_s[g] = h;
      lstm_out[((long)b*CT + t)*128 + g] = h;
    }
    __syncthreads();
  }
}

// ---------------- w: dot over [bert_vec, kc, ia] segments of rnn ----------------
__global__ void w_kernel(const float* __restrict__ rnn, const float* __restrict__ Wt,
                         const float* __restrict__ bt0, float* __restrict__ wbuf)
{
  int bt = blockIdx.x; int lane = threadIdx.x; // 64 threads
  float acc = 0.f;
  for (int i = lane; i < 250; i += 64) {
    float f;
    if (i < 100)      f = rnn[(long)bt*950 + 850 + i];
    else if (i < 150) f = rnn[(long)bt*950 + (i - 100)];
    else              f = rnn[(long)bt*950 + 250 + (i - 150)];
    acc = fmaf(Wt[i], f, acc);
  }
  acc = wredsum(acc);
  if (lane == 0) wbuf[bt] = acc + bt0[0];
}

__global__ void transpose_wfc(const float* __restrict__ Wfc, float* __restrict__ WfcT)
{
  int i = blockIdx.x*256 + threadIdx.x;
  if (i < 100*378) { int o = i / 378, q = i % 378; WfcT[q*100 + o] = Wfc[i]; }
}

// ---------------- final: causal attention + attended + FC + sigmoid ----------------
__global__ __launch_bounds__(256) void final_kernel(
    const float* __restrict__ x, const float* __restrict__ wbuf,
    const float* __restrict__ lstm_out, const float* __restrict__ WfcT,
    const float* __restrict__ bfc, float* __restrict__ out)
{
  int bt = blockIdx.x; int b = bt / CT, i = bt % CT;
  int tid = threadIdx.x;
  __shared__ float p_s[CT];
  __shared__ float feat_s[384];
  if (tid < 64) {
    bool h1 = (64 + tid) < CT;
    float v0 = (tid <= i) ? wbuf[(long)b*CT + tid] : -3.0e38f;
    float v1 = (h1 && (64 + tid) <= i) ? wbuf[(long)b*CT + 64 + tid] : -3.0e38f;
    float mx = wredmax(fmaxf(v0, v1));
    float e0 = (tid <= i) ? __expf(v0 - mx) : 0.f;
    float e1 = (h1 && (64 + tid) <= i) ? __expf(v1 - mx) : 0.f;
    float s = wredsum(e0 + e1);
    float inv = 1.f / s;
    p_s[tid] = e0 * inv;
    if (h1) p_s[64 + tid] = e1 * inv;
  }
  __syncthreads();
  if (tid < CHID) {
    float cur = 0.f;
    #pragma unroll 4
    for (int j = 0; j <= i; ++j) cur = fmaf(p_s[j], lstm_out[((long)b*CT + j)*CHID + tid], cur);
    float l = lstm_out[((long)b*CT + i)*CHID + tid];
    float att;
    if (i == 0) att = l;
    else { att = 0.5f * l; if (i <= CT - 2) att = fmaf(0.5f, cur, att); }
    feat_s[250 + tid] = att;
  }
  for (int q = tid; q < 250; q += 256)
    feat_s[q] = (q < 200) ? x[(long)bt*XCH + q] : x[(long)bt*XCH + 1280 + (q - 200)];
  __syncthreads();
  if (tid < 100) {
    float acc = bfc[tid];
    #pragma unroll 4
    for (int q = 0; q < 378; ++q) acc = fmaf(WfcT[q*100 + tid], feat_s[q], acc);
    out[(long)bt*100 + tid] = fsigmoid(acc);
  }
}

extern "C" void kernel_launch(void* const* d_in, const int* in_sizes, int n_in,
                              void* d_out, int out_size, void* d_ws, size_t ws_size,
                              hipStream_t stream) {
  (void)in_sizes; (void)n_in; (void)out_size; (void)ws_size;
  const float* x        = (const float*)d_in[0];
  const float* node_emb = (const float*)d_in[1];
  const float* path_emb = (const float*)d_in[2];
  const float* Wb       = (const float*)d_in[3];
  const float* bb       = (const float*)d_in[4];
  const float* Wna      = (const float*)d_in[5];
  const float* bna      = (const float*)d_in[6];
  const float* Wia      = (const float*)d_in[7];
  const float* bia      = (const float*)d_in[8];
  const float* Wattn    = (const float*)d_in[9];
  const float* battn    = (const float*)d_in[10];
  const float* kc_emb   = (const float*)d_in[11];
  const float* Wt       = (const float*)d_in[12];
  const float* bt0      = (const float*)d_in[13];
  const float* Wih      = (const float*)d_in[14];
  const float* Whh      = (const float*)d_in[15];
  const float* bih      = (const float*)d_in[16];
  const float* bhh      = (const float*)d_in[17];
  const float* Wfc      = (const float*)d_in[18];
  const float* bfc      = (const float*)d_in[19];
  float* out = (float*)d_out;

  // workspace carve-out (bytes, 256-aligned)
  char* cur = (char*)d_ws;
  auto alloc = [&](size_t bytes)->char* {
    char* p = cur; cur += (bytes + 255) & ~(size_t)255; return p;
  };
  ushort_t* T0A = (ushort_t*)alloc((size_t)NNODE*512*2);
  ushort_t* T0C = (ushort_t*)alloc((size_t)NNODE*512*2);
  ushort_t* TPP = (ushort_t*)alloc((size_t)NPATH*512*2);
  ushort_t* VA  = (ushort_t*)alloc((size_t)NNODE*224*2);
  ushort_t* VC  = (ushort_t*)alloc((size_t)NNODE*224*2);
  ushort_t* VP  = (ushort_t*)alloc((size_t)NPATH*224*2);
  ushort_t* RB  = (ushort_t*)alloc((size_t)NBT*512*2);
  ushort_t* RWB = (ushort_t*)alloc((size_t)NBT*112*2);
  ushort_t* WAB = (ushort_t*)alloc(512*2);
  float* cwT  = (float*)alloc((size_t)NBT*100*4);
  float* awT  = (float*)alloc((size_t)NBT*100*4);
  float* rnn  = (float*)alloc((size_t)NBT*950*4);
  float* pre  = (float*)alloc((size_t)NBT*512*4);
  float* lstm = (float*)alloc((size_t)NBT*128*4);
  float* wbuf = (float*)alloc((size_t)NBT*4);
  float* WfcT = (float*)alloc((size_t)378*100*4);

  auto gg = [](int M, int Npad){ return dim3((unsigned)((M+127)/128), (unsigned)((Npad+63)/64)); };

  // pack embeddings + Wattn
  pack_emb<<<(NNODE*112+255)/256, 256, 0, stream>>>(node_emb, VA, NNODE);
  pack_emb<<<(NNODE*112+255)/256, 256, 0, stream>>>(node_emb, VC, NNODE);
  pack_emb<<<(NPATH*112+255)/256, 256, 0, stream>>>(path_emb, VP, NPATH);
  pack_wattn<<<2, 256, 0, stream>>>(Wattn, WAB);

  // table GEMMs (Wna/Wia pushed through gathers), bf16 outputs
  gemm_mfma<true><<<gg(NNODE,512),256,0,stream>>>(node_emb,100, Wna,    500, T0A,    512, NNODE,500,512,100, nullptr,nullptr);
  gemm_mfma<true><<<gg(NNODE,512),256,0,stream>>>(node_emb,100, Wna+100,500, T0C,    512, NNODE,500,512,100, nullptr,nullptr);
  gemm_mfma<true><<<gg(NPATH,512),256,0,stream>>>(path_emb,100, Wna+200,500, TPP,    512, NPATH,500,512,100, nullptr,nullptr);
  gemm_mfma<true><<<gg(NNODE,112),256,0,stream>>>(node_emb,100, Wia,    500, VA+112, 224, NNODE,100,112,100, nullptr,nullptr);
  gemm_mfma<true><<<gg(NNODE,112),256,0,stream>>>(node_emb,100, Wia+100,500, VC+112, 224, NNODE,100,112,100, nullptr,nullptr);
  gemm_mfma<true><<<gg(NPATH,112),256,0,stream>>>(path_emb,100, Wia+200,500, VP+112, 224, NPATH,100,112,100, nullptr,nullptr);
  // per-(b,t) contributions (biases folded)
  gemm_mfma<true><<<gg(NBT,512),256,0,stream>>>(x,1330, Wna+300,500, RB,  512, NBT,500,512,200, bna,nullptr);
  gemm_mfma<true><<<gg(NBT,112),256,0,stream>>>(x,1330, Wia+300,500, RWB, 112, NBT,100,112,200, bia,nullptr);
  // bert_vec directly into rnn[850:950] (fp32)
  gemm_mfma<false><<<gg(NBT,100),256,0,stream>>>(x+500,1330, Wb,768, rnn+850, 950, NBT,100,100,768, bb,nullptr);

  cw2_kernel<<<NBT,256,0,stream>>>(x, T0A, T0C, TPP, RB, WAB, battn, cwT);
  aw_kernel<<<CB*CMCL,64,0,stream>>>(cwT, awT);
  fuse2_kernel<<<NBT,256,0,stream>>>(x, VA, VC, VP, RWB, awT, kc_emb, rnn);

  // LSTM pre-activations (fp32 out)
  gemm_mfma<false><<<gg(NBT,512),256,0,stream>>>(rnn,950, Wih,950, pre, 512, NBT,512,512,950, bih,bhh);
  lstm_kernel<<<CB,512,0,stream>>>(pre, Whh, lstm);

  w_kernel<<<NBT,64,0,stream>>>(rnn, Wt, bt0, wbuf);
  transpose_wfc<<<(100*378+255)/256,256,0,stream>>>(Wfc, WfcT);
  final_kernel<<<NBT,256,0,stream>>>(x, wbuf, lstm, WfcT, bfc, out);
}

// Round 3
// 818.531 us; speedup vs baseline: 1.3123x; 1.1980x over previous
//
#include <hip/hip_runtime.h>
#include <math.h>

typedef unsigned short ushort_t;
typedef __attribute__((ext_vector_type(8))) short bf16x8;
typedef __attribute__((ext_vector_type(4))) float f32x4;

// Problem constants
constexpr int CB = 16, CT = 100, CMCL = 100, CDIN = 200;
constexpr int CKC = 50, CHID = 128;
constexpr int XCH = 1330;
constexpr int NBT = CB * CT;       // 1600
constexpr int NNODE = 10002, NPATH = 20002;
constexpr int TRS = 114;           // tr_s ushort stride: 57 dwords, odd -> conflict-free

__device__ __forceinline__ float frcp(float v){ return __builtin_amdgcn_rcpf(v); }
__device__ __forceinline__ float fsigmoid(float v){ return frcp(1.f + __expf(-v)); }
__device__ __forceinline__ float ftanh_(float v){
  float e = __expf(-2.f*fabsf(v));
  return copysignf((1.f - e) * frcp(1.f + e), v);
}
__device__ __forceinline__ float wredsum(float v){
  #pragma unroll
  for (int off = 32; off; off >>= 1) v += __shfl_xor(v, off);
  return v;
}
__device__ __forceinline__ float wredmax(float v){
  #pragma unroll
  for (int off = 32; off; off >>= 1) v = fmaxf(v, __shfl_xor(v, off));
  return v;
}
__device__ __forceinline__ ushort_t f2b(float f){
  union { float f; unsigned u; } c{f};
  return (ushort_t)((c.u + 0x7FFFu + ((c.u >> 16) & 1u)) >> 16);
}
__device__ __forceinline__ float b2f(unsigned hbits){
  union { unsigned u; float f; } c{hbits << 16};
  return c.f;
}
__device__ __forceinline__ void b8f(const ushort_t* p, float* o){
  uint4 v = *reinterpret_cast<const uint4*>(p);
  o[0]=b2f(v.x & 0xFFFFu); o[1]=b2f(v.x >> 16);
  o[2]=b2f(v.y & 0xFFFFu); o[3]=b2f(v.y >> 16);
  o[4]=b2f(v.z & 0xFFFFu); o[5]=b2f(v.z >> 16);
  o[6]=b2f(v.w & 0xFFFFu); o[7]=b2f(v.w >> 16);
}

// ---------------- MFMA bf16 GEMM: C = A(MxK,f32) * B(NxK,f32)^T (+bias), out f32 or bf16 ----------------
template<bool OUT_BF16>
__global__ __launch_bounds__(256) void gemm_mfma(
    const float* __restrict__ A, int lda,
    const float* __restrict__ B, int ldb,
    void* __restrict__ Cv, int ldc,
    int M, int N, int Npad, int K,
    const float* __restrict__ bias1, const float* __restrict__ bias2)
{
  __shared__ ushort_t As[128][40];
  __shared__ ushort_t Bs[64][40];
  const int tid = threadIdx.x;
  const int lane = tid & 63, wid = tid >> 6;
  const int wm = wid & 1, wn = wid >> 1;
  const int bm = blockIdx.x * 128, bn = blockIdx.y * 64;
  const int lr = lane & 15, lk = (lane >> 4) * 8;

  f32x4 acc[4][2];
  #pragma unroll
  for (int i = 0; i < 4; ++i)
    #pragma unroll
    for (int j = 0; j < 2; ++j) acc[i][j] = f32x4{0.f,0.f,0.f,0.f};

  const int arow = tid >> 1, akh = (tid & 1) * 16;
  const int brow = tid >> 2, bkh = (tid & 3) * 8;
  const int nk = (K + 31) / 32;
  for (int ks = 0; ks < nk; ++ks) {
    const int k0 = ks * 32;
    {
      int gm = bm + arow;
      const float* ap = A + (long)gm * lda + k0 + akh;
      #pragma unroll
      for (int j = 0; j < 8; ++j) {
        int kk = k0 + akh + 2*j;
        float2 v = make_float2(0.f, 0.f);
        if (gm < M && kk + 2 <= K) v = *reinterpret_cast<const float2*>(ap + 2*j);
        As[arow][akh + 2*j]     = f2b(v.x);
        As[arow][akh + 2*j + 1] = f2b(v.y);
      }
    }
    {
      int gn = bn + brow;
      const float* bp = B + (long)gn * ldb + k0 + bkh;
      #pragma unroll
      for (int j = 0; j < 4; ++j) {
        int kk = k0 + bkh + 2*j;
        float2 v = make_float2(0.f, 0.f);
        if (gn < N && kk + 2 <= K) v = *reinterpret_cast<const float2*>(bp + 2*j);
        Bs[brow][bkh + 2*j]     = f2b(v.x);
        Bs[brow][bkh + 2*j + 1] = f2b(v.y);
      }
    }
    __syncthreads();
    bf16x8 af[4], bf[2];
    #pragma unroll
    for (int i = 0; i < 4; ++i)
      af[i] = *reinterpret_cast<const bf16x8*>(&As[wm*64 + i*16 + lr][lk]);
    #pragma unroll
    for (int j = 0; j < 2; ++j)
      bf[j] = *reinterpret_cast<const bf16x8*>(&Bs[wn*32 + j*16 + lr][lk]);
    #pragma unroll
    for (int i = 0; i < 4; ++i)
      #pragma unroll
      for (int j = 0; j < 2; ++j)
        acc[i][j] = __builtin_amdgcn_mfma_f32_16x16x32_bf16(af[i], bf[j], acc[i][j], 0, 0, 0);
    __syncthreads();
  }
  #pragma unroll
  for (int i = 0; i < 4; ++i) {
    #pragma unroll
    for (int j = 0; j < 2; ++j) {
      #pragma unroll
      for (int r = 0; r < 4; ++r) {
        int gr = bm + wm*64 + i*16 + (lane >> 4)*4 + r;
        int gc = bn + wn*32 + j*16 + lr;
        if (gr < M && gc < Npad) {
          float v = acc[i][j][r];
          if (gc < N) {
            if (bias1) v += bias1[gc];
            if (bias2) v += bias2[gc];
          } else v = 0.f;
          if (OUT_BF16) ((ushort_t*)Cv)[(long)gr * ldc + gc] = f2b(v);
          else          ((float*)Cv)[(long)gr * ldc + gc]  = v;
        }
      }
    }
  }
}

// ---------------- pack embeddings: cols 0..111 of a `stride`-wide bf16 row ----------------
__global__ void pack_emb(const float* __restrict__ emb, ushort_t* __restrict__ V, int rows, int stride)
{
  int i = blockIdx.x * 256 + threadIdx.x;
  int r = i / 112, c = i % 112;
  if (r < rows) V[(long)r*stride + c] = (c < 100) ? f2b(emb[(long)r*100 + c]) : (ushort_t)0;
}
__global__ void pack_wattn(const float* __restrict__ Wattn, ushort_t* __restrict__ wab)
{
  int i = blockIdx.x * 256 + threadIdx.x;
  if (i < 512) wab[i] = (i < 500) ? f2b(Wattn[i]) : (ushort_t)0;
}

// ---------------- cw: per (b,t), all m: Wattn . tanh(T0A[a]+T0C[c]+TPP[p]+R) ----------------
__global__ __launch_bounds__(256) void cw2_kernel(
    const float* __restrict__ x, const ushort_t* __restrict__ T0A,
    const ushort_t* __restrict__ T0C, const ushort_t* __restrict__ TPP,
    const ushort_t* __restrict__ RB, const ushort_t* __restrict__ WAB,
    const float* __restrict__ battn, float* __restrict__ cwT)
{
  int bt = blockIdx.x, b = bt / CT, t = bt % CT;
  int tid = threadIdx.x, w = tid >> 6, lane = tid & 63;
  __shared__ int idx_s[300];
  for (int i = tid; i < 300; i += 256) idx_s[i] = (int)x[(long)bt*XCH + 200 + i];
  float rseg[8], wseg[8];
  b8f(RB + (long)bt*512 + lane*8, rseg);
  b8f(WAB + lane*8, wseg);
  __syncthreads();
  float bat = battn[0];

  uint4 A0, C0, P0, A1, C1, P1;
  auto issue = [&](int m, uint4& A, uint4& C, uint4& P){
    if (m < CMCL) {
      int ai = idx_s[3*m], pi = idx_s[3*m+1], ci = idx_s[3*m+2];
      A = *reinterpret_cast<const uint4*>(T0A + (long)ai*512 + lane*8);
      C = *reinterpret_cast<const uint4*>(T0C + (long)ci*512 + lane*8);
      P = *reinterpret_cast<const uint4*>(TPP + (long)pi*512 + lane*8);
    }
  };
  auto proc = [&](int m, const uint4& A, const uint4& C, const uint4& P){
    if (m >= CMCL) return;
    const unsigned ua[4] = {A.x, A.y, A.z, A.w};
    const unsigned uc[4] = {C.x, C.y, C.z, C.w};
    const unsigned up[4] = {P.x, P.y, P.z, P.w};
    float acc = 0.f;
    #pragma unroll
    for (int jj = 0; jj < 4; ++jj) {
      float lo = b2f(ua[jj] & 0xffffu) + b2f(uc[jj] & 0xffffu) + b2f(up[jj] & 0xffffu) + rseg[2*jj];
      float hi = b2f(ua[jj] >> 16)     + b2f(uc[jj] >> 16)     + b2f(up[jj] >> 16)     + rseg[2*jj+1];
      acc = fmaf(ftanh_(lo), wseg[2*jj], acc);
      acc = fmaf(ftanh_(hi), wseg[2*jj+1], acc);
    }
    acc = wredsum(acc);
    if (lane == 0) cwT[((long)b*CMCL + m)*CT + t] = acc + bat;
  };

  issue(w, A0, C0, P0);
  for (int it = 0; it < 25; it += 2) {
    int m0 = w + it*4;
    issue(m0 + 4, A1, C1, P1);
    proc(m0, A0, C0, P0);
    issue(m0 + 8, A0, C0, P0);
    proc(m0 + 4, A1, C1, P1);
  }
}

// ---------------- aw: softmax over t for each (b,m) ----------------
__global__ void aw_kernel(const float* __restrict__ cwT, float* __restrict__ awT)
{
  int bm = blockIdx.x; int lane = threadIdx.x;   // 64 threads
  const float* row = cwT + (long)bm * CT;
  bool h1 = lane < (CT - 64);
  float v0 = row[lane];
  float v1 = h1 ? row[64 + lane] : -3.0e38f;
  float mx = wredmax(fmaxf(v0, v1));
  float e0 = __expf(v0 - mx);
  float e1 = h1 ? __expf(v1 - mx) : 0.f;
  float s = wredsum(e0 + e1);
  float inv = frcp(s);
  awT[(long)bm*CT + lane] = e0 * inv;
  if (h1) awT[(long)bm*CT + 64 + lane] = e1 * inv;
}

// ---------------- fused: na + trans(LDS bf16) + kc-attention -> rnn[0:850] ----------------
__global__ __launch_bounds__(256) void fuse2_kernel(
    const float* __restrict__ x,
    const ushort_t* __restrict__ VAC, const ushort_t* __restrict__ VP,
    const ushort_t* __restrict__ RWB, const float* __restrict__ awT,
    const float* __restrict__ kc_emb, float* __restrict__ rnn)
{
  int bt = blockIdx.x, b = bt / CT, t = bt % CT;
  int tid = threadIdx.x, w = tid >> 6, lane = tid & 63;
  int sub = lane >> 5, li = lane & 31;

  __shared__ ushort_t tr_s[100*TRS];   // 22800 B
  __shared__ float nacc[4][344];
  __shared__ float ia_red[4][104];
  __shared__ float aw_s[100];
  __shared__ int   idx_s[300];
  __shared__ float kcl[CKC];
  __shared__ int   act_k[CKC];
  __shared__ int   nact_s;
  __shared__ float kcn_s, awsum_s;

  for (int i = tid; i < 300; i += 256) idx_s[i] = (int)x[(long)bt*XCH + 200 + i];
  if (tid < 100) aw_s[tid] = awT[((long)b*CMCL + tid)*CT + t];
  if (tid < CKC) kcl[tid] = x[(long)bt*XCH + 1280 + tid];
  __syncthreads();
  if (tid == 0) {
    float kcn = 0.f; int na = 0;
    for (int k = 0; k < CKC; ++k) { float v = kcl[k]; kcn += v; if (v != 0.f) act_k[na++] = k; }
    nact_s = na; kcn_s = (kcn == 0.f) ? 1.f : kcn;
    float s = 0.f;
    for (int m = 0; m < CMCL; ++m) s += aw_s[m];
    awsum_s = s;
  }
  float rwseg[8];
  if (li >= 14 && li < 28) b8f(RWB + (long)bt*112 + (li-14)*8, rwseg);
  __syncthreads();

  // ---- gather phase: 8 m per iteration (4 waves x 2 sub-halves), 2-stage pipeline ----
  float na_a[8] = {}, na_c[8] = {}, na_p[8] = {};
  const bool gv = (li < 28);
  uint4 A0, C0, P0, A1, C1, P1;
  auto g_issue = [&](int m, uint4& A, uint4& C, uint4& P){
    if (m < CMCL && gv) {
      int ai = idx_s[3*m], pi = idx_s[3*m+1], ci = idx_s[3*m+2];
      int eo = li*8, uo = (li-14)*8;
      A = *reinterpret_cast<const uint4*>(VAC + (long)ai*336 + ((li<14) ? eo : 112 + uo));
      C = *reinterpret_cast<const uint4*>(VAC + (long)ci*336 + ((li<14) ? eo : 224 + uo));
      P = *reinterpret_cast<const uint4*>(VP  + (long)pi*224 + eo);
    }
  };
  auto g_proc = [&](int m, const uint4& A, const uint4& C, const uint4& P){
    if (m >= CMCL || !gv) return;
    const unsigned ua[4] = {A.x, A.y, A.z, A.w};
    const unsigned uc[4] = {C.x, C.y, C.z, C.w};
    const unsigned up[4] = {P.x, P.y, P.z, P.w};
    if (li < 14) {
      float awm = aw_s[m];
      #pragma unroll
      for (int jj = 0; jj < 4; ++jj) {
        na_a[2*jj]   = fmaf(awm, b2f(ua[jj] & 0xffffu), na_a[2*jj]);
        na_a[2*jj+1] = fmaf(awm, b2f(ua[jj] >> 16),     na_a[2*jj+1]);
        na_c[2*jj]   = fmaf(awm, b2f(uc[jj] & 0xffffu), na_c[2*jj]);
        na_c[2*jj+1] = fmaf(awm, b2f(uc[jj] >> 16),     na_c[2*jj+1]);
        na_p[2*jj]   = fmaf(awm, b2f(up[jj] & 0xffffu), na_p[2*jj]);
        na_p[2*jj+1] = fmaf(awm, b2f(up[jj] >> 16),     na_p[2*jj+1]);
      }
    } else {
      unsigned* d32 = reinterpret_cast<unsigned*>(&tr_s[m*TRS + (li-14)*8]);
      #pragma unroll
      for (int jj = 0; jj < 4; ++jj) {
        float lo = b2f(ua[jj] & 0xffffu) + b2f(uc[jj] & 0xffffu) + b2f(up[jj] & 0xffffu) + rwseg[2*jj];
        float hi = b2f(ua[jj] >> 16)     + b2f(uc[jj] >> 16)     + b2f(up[jj] >> 16)     + rwseg[2*jj+1];
        d32[jj] = (unsigned)f2b(lo) | ((unsigned)f2b(hi) << 16);
      }
    }
  };
  const int mb = w*2 + sub;
  g_issue(mb, A0, C0, P0);
  for (int it = 0; it < 13; it += 2) {
    g_issue((it+1)*8 + mb, A1, C1, P1);
    g_proc(it*8 + mb, A0, C0, P0);
    g_issue((it+2)*8 + mb, A0, C0, P0);
    g_proc((it+1)*8 + mb, A1, C1, P1);
  }
  // combine sub-halves of na
  #pragma unroll
  for (int j = 0; j < 8; ++j) {
    na_a[j] += __shfl_xor(na_a[j], 32);
    na_c[j] += __shfl_xor(na_c[j], 32);
    na_p[j] += __shfl_xor(na_p[j], 32);
  }
  if (lane < 14) {
    #pragma unroll
    for (int j = 0; j < 8; ++j) {
      nacc[w][      lane*8 + j] = na_a[j];
      nacc[w][112 + lane*8 + j] = na_c[j];
      nacc[w][224 + lane*8 + j] = na_p[j];
    }
  }
  __syncthreads();

  // ---- na epilogue + passthroughs ----
  for (int q = tid; q < 336; q += 256) {
    float v = nacc[0][q] + nacc[1][q] + nacc[2][q] + nacc[3][q];
    int seg = q / 112, col = q % 112;
    if (col < 100) rnn[(long)bt*950 + 350 + seg*100 + col] = v;
  }
  for (int q = tid; q < CDIN; q += 256) {
    float xv = x[(long)bt*XCH + q];
    rnn[(long)bt*950 + 50 + q] = xv;
    rnn[(long)bt*950 + 650 + q] = awsum_s * xv;
  }
  if (tid < CKC) rnn[(long)bt*950 + tid] = kcl[tid];

  // ---- kc attention (dword-pair LDS reads, conflict-free stride) ----
  float ia0 = 0.f, ia1 = 0.f;
  const bool vrow1 = lane < 36;   // owns row 64+lane
  const bool vpv   = lane < 50;   // owns dims 2*lane, 2*lane+1
  const int nact = nact_s;
  const unsigned* tr32_0 = reinterpret_cast<const unsigned*>(&tr_s[lane*TRS]);
  const unsigned* tr32_1 = reinterpret_cast<const unsigned*>(&tr_s[(64+lane)*TRS]);
  const unsigned* tr32   = reinterpret_cast<const unsigned*>(tr_s);
  for (int ki = w; ki < nact; ki += 4) {
    int k = act_k[ki];
    float kck = kcl[k];
    const float* ke = kc_emb + (long)k*100;
    float s0 = 0.f, s1 = 0.f;
    #pragma unroll 5
    for (int dh = 0; dh < 50; ++dh) {
      float k0 = ke[2*dh], k1 = ke[2*dh+1];
      unsigned u0 = tr32_0[dh];
      s0 = fmaf(k0, b2f(u0 & 0xffffu), s0);
      s0 = fmaf(k1, b2f(u0 >> 16), s0);
      if (vrow1) {
        unsigned u1 = tr32_1[dh];
        s1 = fmaf(k0, b2f(u1 & 0xffffu), s1);
        s1 = fmaf(k1, b2f(u1 >> 16), s1);
      }
    }
    s0 *= kck; s1 *= kck;
    float mx = wredmax(fmaxf(s0, vrow1 ? s1 : -3.0e38f));
    float p0e = __expf(s0 - mx);
    float p1e = vrow1 ? __expf(s1 - mx) : 0.f;
    float sm = wredsum(p0e + p1e);
    float inv = kck * frcp(sm);
    p0e *= inv; p1e *= inv;
    #pragma unroll 4
    for (int m = 0; m < CMCL; ++m) {
      float pm = (m < 64) ? __shfl(p0e, m) : __shfl(p1e, m - 64);
      if (vpv) {
        unsigned u = tr32[m*57 + lane];
        ia0 = fmaf(pm, b2f(u & 0xffffu), ia0);
        ia1 = fmaf(pm, b2f(u >> 16), ia1);
      }
    }
  }
  if (vpv) { ia_red[w][2*lane] = ia0; ia_red[w][2*lane+1] = ia1; }
  __syncthreads();
  if (tid < 100) {
    float v = (ia_red[0][tid] + ia_red[1][tid] + ia_red[2][tid] + ia_red[3][tid]) * frcp(kcn_s);
    rnn[(long)bt*950 + 250 + tid] = v;
  }
}

// ---------------- LSTM: one block per batch, Whh rows in registers ----------------
__global__ __launch_bounds__(512) void lstm_kernel(
    const float* __restrict__ pre, const float* __restrict__ Whh,
    float* __restrict__ lstm_out)
{
  int b = blockIdx.x; int g = threadIdx.x;  // 0..511
  __shared__ __align__(16) float h_s[128];
  __shared__ float g_s[512];
  float4 wr[32];
  #pragma unroll
  for (int j = 0; j < 32; ++j) wr[j] = reinterpret_cast<const float4*>(Whh + (long)g*128)[j];
  float c_reg = 0.f;
  if (g < 128) h_s[g] = 0.f;
  float pf = pre[(long)b*CT*512 + g];
  __syncthreads();
  for (int t = 0; t < CT; ++t) {
    float gv_in = pf;
    if (t + 1 < CT) pf = pre[((long)b*CT + t + 1)*512 + g];
    float s0=0,s1=0,s2=0,s3=0;
    #pragma unroll
    for (int j = 0; j < 32; ++j) {
      float4 hh = reinterpret_cast<const float4*>(h_s)[j];
      s0 = fmaf(wr[j].x, hh.x, s0);
      s1 = fmaf(wr[j].y, hh.y, s1);
      s2 = fmaf(wr[j].z, hh.z, s2);
      s3 = fmaf(wr[j].w, hh.w, s3);
    }
    g_s[g] = gv_in + ((s0+s1)+(s2+s3));
    __syncthreads();
    if (g < 128) {
      float ig = fsigmoid(g_s[g]);
      float fg = fsigmoid(g_s[128+g]);
      float gg = ftanh_(g_s[256+g]);
      float og = fsigmoid(g_s[384+g]);
      c_reg = fg*c_reg + ig*gg;
      float h = og * ftanh_(c_reg);
      h_s[g] = h;
      lstm_out[((long)b*CT + t)*128 + g] = h;
    }
    __syncthreads();
  }
}

// ---------------- w: dot over [bert_vec, kc, ia] segments of rnn ----------------
__global__ void w_kernel(const float* __restrict__ rnn, const float* __restrict__ Wt,
                         const float* __restrict__ bt0, float* __restrict__ wbuf)
{
  int bt = blockIdx.x; int lane = threadIdx.x; // 64 threads
  float acc = 0.f;
  for (int i = lane; i < 250; i += 64) {
    float f;
    if (i < 100)      f = rnn[(long)bt*950 + 850 + i];
    else if (i < 150) f = rnn[(long)bt*950 + (i - 100)];
    else              f = rnn[(long)bt*950 + 250 + (i - 150)];
    acc = fmaf(Wt[i], f, acc);
  }
  acc = wredsum(acc);
  if (lane == 0) wbuf[bt] = acc + bt0[0];
}

__global__ void transpose_wfc(const float* __restrict__ Wfc, float* __restrict__ WfcT)
{
  int i = blockIdx.x*256 + threadIdx.x;
  if (i < 100*378) { int o = i / 378, q = i % 378; WfcT[q*100 + o] = Wfc[i]; }
}

// ---------------- final: causal attention + attended + FC + sigmoid ----------------
__global__ __launch_bounds__(256) void final_kernel(
    const float* __restrict__ x, const float* __restrict__ wbuf,
    const float* __restrict__ lstm_out, const float* __restrict__ WfcT,
    const float* __restrict__ bfc, float* __restrict__ out)
{
  int bt = blockIdx.x; int b = bt / CT, i = bt % CT;
  int tid = threadIdx.x;
  __shared__ float p_s[CT];
  __shared__ float feat_s[384];
  if (tid < 64) {
    bool h1 = (64 + tid) < CT;
    float v0 = (tid <= i) ? wbuf[(long)b*CT + tid] : -3.0e38f;
    float v1 = (h1 && (64 + tid) <= i) ? wbuf[(long)b*CT + 64 + tid] : -3.0e38f;
    float mx = wredmax(fmaxf(v0, v1));
    float e0 = (tid <= i) ? __expf(v0 - mx) : 0.f;
    float e1 = (h1 && (64 + tid) <= i) ? __expf(v1 - mx) : 0.f;
    float s = wredsum(e0 + e1);
    float inv = frcp(s);
    p_s[tid] = e0 * inv;
    if (h1) p_s[64 + tid] = e1 * inv;
  }
  __syncthreads();
  if (tid < CHID) {
    float cur = 0.f;
    #pragma unroll 4
    for (int j = 0; j <= i; ++j) cur = fmaf(p_s[j], lstm_out[((long)b*CT + j)*CHID + tid], cur);
    float l = lstm_out[((long)b*CT + i)*CHID + tid];
    float att;
    if (i == 0) att = l;
    else { att = 0.5f * l; if (i <= CT - 2) att = fmaf(0.5f, cur, att); }
    feat_s[250 + tid] = att;
  }
  for (int q = tid; q < 250; q += 256)
    feat_s[q] = (q < 200) ? x[(long)bt*XCH + q] : x[(long)bt*XCH + 1280 + (q - 200)];
  __syncthreads();
  if (tid < 100) {
    float acc = bfc[tid];
    #pragma unroll 4
    for (int q = 0; q < 378; ++q) acc = fmaf(WfcT[q*100 + tid], feat_s[q], acc);
    out[(long)bt*100 + tid] = fsigmoid(acc);
  }
}

extern "C" void kernel_launch(void* const* d_in, const int* in_sizes, int n_in,
                              void* d_out, int out_size, void* d_ws, size_t ws_size,
                              hipStream_t stream) {
  (void)in_sizes; (void)n_in; (void)out_size; (void)ws_size;
  const float* x        = (const float*)d_in[0];
  const float* node_emb = (const float*)d_in[1];
  const float* path_emb = (const float*)d_in[2];
  const float* Wb       = (const float*)d_in[3];
  const float* bb       = (const float*)d_in[4];
  const float* Wna      = (const float*)d_in[5];
  const float* bna      = (const float*)d_in[6];
  const float* Wia      = (const float*)d_in[7];
  const float* bia      = (const float*)d_in[8];
  const float* Wattn    = (const float*)d_in[9];
  const float* battn    = (const float*)d_in[10];
  const float* kc_emb   = (const float*)d_in[11];
  const float* Wt       = (const float*)d_in[12];
  const float* bt0      = (const float*)d_in[13];
  const float* Wih      = (const float*)d_in[14];
  const float* Whh      = (const float*)d_in[15];
  const float* bih      = (const float*)d_in[16];
  const float* bhh      = (const float*)d_in[17];
  const float* Wfc      = (const float*)d_in[18];
  const float* bfc      = (const float*)d_in[19];
  float* out = (float*)d_out;

  char* cur = (char*)d_ws;
  auto alloc = [&](size_t bytes)->char* {
    char* p = cur; cur += (bytes + 255) & ~(size_t)255; return p;
  };
  ushort_t* T0A = (ushort_t*)alloc((size_t)NNODE*512*2);
  ushort_t* T0C = (ushort_t*)alloc((size_t)NNODE*512*2);
  ushort_t* TPP = (ushort_t*)alloc((size_t)NPATH*512*2);
  ushort_t* VAC = (ushort_t*)alloc((size_t)NNODE*336*2);   // [emb|pad|Ua|pad|Uc|pad]
  ushort_t* VP  = (ushort_t*)alloc((size_t)NPATH*224*2);   // [emb|pad|Up|pad]
  ushort_t* RB  = (ushort_t*)alloc((size_t)NBT*512*2);
  ushort_t* RWB = (ushort_t*)alloc((size_t)NBT*112*2);
  ushort_t* WAB = (ushort_t*)alloc(512*2);
  float* cwT  = (float*)alloc((size_t)NBT*100*4);
  float* awT  = (float*)alloc((size_t)NBT*100*4);
  float* rnn  = (float*)alloc((size_t)NBT*950*4);
  float* pre  = (float*)alloc((size_t)NBT*512*4);
  float* lstm = (float*)alloc((size_t)NBT*128*4);
  float* wbuf = (float*)alloc((size_t)NBT*4);
  float* WfcT = (float*)alloc((size_t)378*100*4);

  auto gg = [](int M, int Npad){ return dim3((unsigned)((M+127)/128), (unsigned)((Npad+63)/64)); };

  // pack embeddings + Wattn
  pack_emb<<<(NNODE*112+255)/256, 256, 0, stream>>>(node_emb, VAC, NNODE, 336);
  pack_emb<<<(NPATH*112+255)/256, 256, 0, stream>>>(path_emb, VP, NPATH, 224);
  pack_wattn<<<2, 256, 0, stream>>>(Wattn, WAB);

  // table GEMMs (Wna/Wia pushed through gathers), bf16 outputs
  gemm_mfma<true><<<gg(NNODE,512),256,0,stream>>>(node_emb,100, Wna,    500, T0A,     512, NNODE,500,512,100, nullptr,nullptr);
  gemm_mfma<true><<<gg(NNODE,512),256,0,stream>>>(node_emb,100, Wna+100,500, T0C,     512, NNODE,500,512,100, nullptr,nullptr);
  gemm_mfma<true><<<gg(NPATH,512),256,0,stream>>>(path_emb,100, Wna+200,500, TPP,     512, NPATH,500,512,100, nullptr,nullptr);
  gemm_mfma<true><<<gg(NNODE,112),256,0,stream>>>(node_emb,100, Wia,    500, VAC+112, 336, NNODE,100,112,100, nullptr,nullptr);
  gemm_mfma<true><<<gg(NNODE,112),256,0,stream>>>(node_emb,100, Wia+100,500, VAC+224, 336, NNODE,100,112,100, nullptr,nullptr);
  gemm_mfma<true><<<gg(NPATH,112),256,0,stream>>>(path_emb,100, Wia+200,500, VP+112,  224, NPATH,100,112,100, nullptr,nullptr);
  // per-(b,t) contributions (biases folded)
  gemm_mfma<true><<<gg(NBT,512),256,0,stream>>>(x,1330, Wna+300,500, RB,  512, NBT,500,512,200, bna,nullptr);
  gemm_mfma<true><<<gg(NBT,112),256,0,stream>>>(x,1330, Wia+300,500, RWB, 112, NBT,100,112,200, bia,nullptr);
  // bert_vec directly into rnn[850:950] (fp32)
  gemm_mfma<false><<<gg(NBT,100),256,0,stream>>>(x+500,1330, Wb,768, rnn+850, 950, NBT,100,100,768, bb,nullptr);

  cw2_kernel<<<NBT,256,0,stream>>>(x, T0A, T0C, TPP, RB, WAB, battn, cwT);
  aw_kernel<<<CB*CMCL,64,0,stream>>>(cwT, awT);
  fuse2_kernel<<<NBT,256,0,stream>>>(x, VAC, VP, RWB, awT, kc_emb, rnn);

  // LSTM pre-activations (fp32 out)
  gemm_mfma<false><<<gg(NBT,512),256,0,stream>>>(rnn,950, Wih,950, pre, 512, NBT,512,512,950, bih,bhh);
  lstm_kernel<<<CB,512,0,stream>>>(pre, Whh, lstm);

  w_kernel<<<NBT,64,0,stream>>>(rnn, Wt, bt0, wbuf);
  transpose_wfc<<<(100*378+255)/256,256,0,stream>>>(Wfc, WfcT);
  final_kernel<<<NBT,256,0,stream>>>(x, wbuf, lstm, WfcT, bfc, out);
}